// Round 7
// baseline (24.693 us; speedup 1.0000x reference)
//
#include <hip/hip_runtime.h>

// Fixed problem constants
#define T_IN  441000          // samples per (b,c)
#define L1    444416          // after 1st reflect pad
#define PAD1  1536
#define P2    2048
#define POS0  3584            // output g -> pad position g + 3584
#define NB    108             // ceil(441000/4096) output blocks per bc
#define BC    16              // B*C
#define NWG   (NB * BC)       // 1728 = 8*216 (bijective XCD swizzle)

// sin/cos of 2*pi*f, f in revolutions
#if __has_builtin(__builtin_amdgcn_cosf)
#define COS2PI(f) __builtin_amdgcn_cosf(f)
#define SIN2PI(f) __builtin_amdgcn_sinf(f)
#else
#define COS2PI(f) __cosf(6.28318530717958647692f * (f))
#define SIN2PI(f) __sinf(6.28318530717958647692f * (f))
#endif

// Composed reflect-pads: xpad[m] = x[map_idx(m)]
__device__ __forceinline__ int map_idx(int m) {
    int a = m - P2;
    if (a < 0) a = -a;
    else if (a >= L1) a = 2 * L1 - 2 - a;
    int b = a - PAD1;
    if (b < 0) b = -b;
    else if (b >= T_IN) b = 2 * T_IN - 2 - b;
    return b;
}

// One fused kernel. Block = 4096 outputs [4096B, 4096B+4095] of slice bc.
// Frames j in [4B, 4B+7]; pad-span [4096B, 4096B+11264] staged in LDS.
// Phase 3 split around the last barrier: direct term (xs-only) overlaps the
// serial pEO combine; p-term + store after pEO is visible.
__global__ void __launch_bounds__(512, 6) fused_kernel(const float* __restrict__ x,
                                                       float* __restrict__ out) {
    __shared__ __align__(16) float xs[11268];   // 11265 used
    __shared__ __align__(16) float red[8][2][8];
    __shared__ __align__(16) float pEO[2][8];   // [0]=E (even-n), [1]=O; scaled 2/3

    const int lin = blockIdx.x;
    const int wg  = (lin & 7) * (NWG / 8) + (lin >> 3);   // XCD swizzle (bijective)
    const int B   = wg % NB;
    const int bc  = wg / NB;
    const int tid = threadIdx.x;
    const float* xb = x + (size_t)bc * T_IN;
    float*       ob = out + (size_t)bc * T_IN;
    const int padbase = 4096 * B;
    const bool fast = (B >= 1 && B <= 105);     // identity map over whole span

    // ---- Phase 1: stage xs[i] = xpad[padbase + i], i in [0, 11264] ----
    if (fast) {
        const float* src = xb + (padbase - POS0);   // 16B-aligned
        #pragma unroll
        for (int i4 = 0; i4 < 5; ++i4) {
            const int idx = (tid + 512 * i4) * 4;
            *reinterpret_cast<float4*>(&xs[idx]) =
                *reinterpret_cast<const float4*>(&src[idx]);
        }
        if (tid < 256) {
            const int idx = (tid + 2560) * 4;       // floats 10240..11263
            *reinterpret_cast<float4*>(&xs[idx]) =
                *reinterpret_cast<const float4*>(&src[idx]);
        } else if (tid == 256) {
            xs[11264] = src[11264];
        }
    } else {
        for (int i = tid; i <= 11264; i += 512)
            xs[i] = xb[map_idx(padbase + i)];
    }

    // per-thread sincos (hides under staging loads)
    const float c0 = COS2PI((float)tid * (1.0f / 4096.0f));
    const float s0 = SIN2PI((float)tid * (1.0f / 4096.0f));
    const float Hh = 0.70710678118654752440f;
    const float c1 = (c0 - s0) * Hh;   // cos(theta + pi/4)
    const float s1 = (s0 + c0) * Hh;   // sin(theta + pi/4)
    const float wqE[4] = { fmaf(-0.5f, c0, 0.5f), fmaf( 0.5f, s0, 0.5f),
                           fmaf( 0.5f, c0, 0.5f), fmaf(-0.5f, s0, 0.5f) };
    const float wqO[4] = { fmaf(-0.5f, c1, 0.5f), fmaf( 0.5f, s1, 0.5f),
                           fmaf( 0.5f, c1, 0.5f), fmaf(-0.5f, s1, 0.5f) };
    __syncthreads();                                        // B1: xs ready

    // ---- Phase 2: frame E/O partial sums ----
    float acc[8] = {0, 0, 0, 0, 0, 0, 0, 0};
    #pragma unroll
    for (int c4 = 0; c4 < 22; ++c4) {
        const int c = c4 >> 1;
        const float xv = xs[tid + 512 * c4];
        #pragma unroll
        for (int q = 0; q < 4; ++q) {
            const int m = c - q;
            if (m < 0 || m > 7) continue;
            const float w = (c4 & 1) ? wqO[q] : wqE[q];   // compile-time select
            acc[m] = fmaf(xv, w, acc[m]);
        }
    }
    {
        const int wave = tid >> 6, lane = tid & 63;
        #pragma unroll
        for (int m = 0; m < 8; ++m) {
            float s = acc[m];
            s += __shfl_down(s, 32, 64);
            s += __shfl_down(s, 16, 64);
            s += __shfl_down(s,  8, 64);
            s += __shfl_down(s,  4, 64);
            s += __shfl_down(s,  2, 64);   // parity preserved: lane0=even-n, lane1=odd-n
            if (lane < 2) red[m][lane][wave] = s;
        }
    }
    __syncthreads();                                        // B2: red ready

    // serial combine (tid<16) overlapped with direct-term accumulation (all threads)
    if (tid < 16) {
        const int m = tid >> 1, par = tid & 1;
        const float4 r0 = *reinterpret_cast<const float4*>(&red[m][par][0]);
        const float4 r1 = *reinterpret_cast<const float4*>(&red[m][par][4]);
        pEO[par][m] = ((r0.x + r0.y) + (r0.z + r0.w) +
                       (r1.x + r1.y) + (r1.z + r1.w)) * (2.0f / 3.0f);
    }

    const float K = 4096.0f / 3.0f;               // 2048 * 2/3
    float aDir[8];
    float wph[8];
    if (fast) {
        const float cosv[8] = { c0, c1, -s0, -s1, -c0, -c1, s0, s1 };
        float wk2[8];
        #pragma unroll
        for (int p = 0; p < 8; ++p) {
            wph[p] = fmaf(-0.5f, cosv[p], 0.5f);
            wk2[p] = K * wph[p] * wph[p];
        }
        #pragma unroll
        for (int k = 0; k < 8; ++k) {
            const int off = (k + 1) >> 1;                 // jlo - 4B, compile-time
            float a = 0.0f;
            #pragma unroll
            for (int jj = 0; jj < 4; ++jj) {
                const int m = off + jj;                   // 0..7, compile-time
                const int u = (k & 1) ? (6 - 2 * jj) : (7 - 2 * jj);
                const float xv = xs[2048 * m + 512 - tid - 512 * k];
                a = fmaf(wk2[u], xv, a);                  // win^2 * K * x
            }
            aDir[k] = a;
        }
    }
    __syncthreads();                                        // B3: pEO ready

    if (fast) {
        const int sel = (tid & 1) ^ 1;                    // even pos -> O, odd -> E
        const float4 pA = *reinterpret_cast<const float4*>(&pEO[sel][0]);
        const float4 pB = *reinterpret_cast<const float4*>(&pEO[sel][4]);
        const float psel[8] = { pA.x, pA.y, pA.z, pA.w, pB.x, pB.y, pB.z, pB.w };
        #pragma unroll
        for (int k = 0; k < 8; ++k) {
            const int off = (k + 1) >> 1;
            float a = aDir[k];
            #pragma unroll
            for (int jj = 0; jj < 4; ++jj) {
                const int m = off + jj;
                const int u = (k & 1) ? (6 - 2 * jj) : (7 - 2 * jj);
                a = fmaf(wph[u], psel[m], a);             // + win * p_j
            }
            ob[padbase + tid + 512 * k] = a;
        }
    } else {
        #pragma unroll
        for (int k = 0; k < 8; ++k) {
            const int gl = tid + 512 * k;
            const int g  = padbase + gl;
            if (g >= T_IN) continue;
            const int pos = g + POS0;
            int jh = pos >> 10, jl = jh - 3;
            if (jl < 2)   jl = 2;
            if (jh > 432) jh = 432;
            float a = 0.0f;
            for (int j = jl; j <= jh; ++j) {
                const int m = j - 4 * B;                  // staged frame slot
                const int t = pos - (j << 10);            // 0..4095
                const float w = fmaf(-0.5f, COS2PI((float)t * (1.0f / 4096.0f)), 0.5f);
                const float xv = xs[2048 * m + 512 - gl];
                const float p  = (pos & 1) ? pEO[0][m] : pEO[1][m];
                a = fmaf(w, fmaf(K * w, xv, p), a);
            }
            ob[g] = a;
        }
    }
}

extern "C" void kernel_launch(void* const* d_in, const int* in_sizes, int n_in,
                              void* d_out, int out_size, void* d_ws, size_t ws_size,
                              hipStream_t stream) {
    const float* x = (const float*)d_in[0];   // mix (8,2,441000) fp32
    float* out = (float*)d_out;
    fused_kernel<<<dim3(NWG), 512, 0, stream>>>(x, out);
}